// Round 9
// baseline (107.095 us; speedup 1.0000x reference)
//
#include <hip/hip_runtime.h>
#include <hip/hip_bf16.h>
#include <math.h>

#define Bn 4
#define Cn 64
#define Pn 4096   // 64*64
#define QT 32     // q-tile per block
#define PBK 128   // p-block per flash iteration
#define NITER (Pn / PBK)
#define LOG2E 1.4426950408889634f

typedef __attribute__((ext_vector_type(8))) short short8;   // 8 bf16 = 4 VGPRs (MFMA A/B frag)
typedef __attribute__((ext_vector_type(4))) float float4v;  // MFMA C/D frag
typedef unsigned short bfu;

__device__ __forceinline__ bfu f2bf(float x) {
    unsigned u = __float_as_uint(x);
    u = (u + 0x7fffu + ((u >> 16) & 1u)) >> 16;   // RNE; inputs finite
    return (bfu)u;
}

// async global->LDS DMA, 16B per lane; LDS dest = base + lane*16 (wave-uniform base)
__device__ __forceinline__ void async_load16(const bfu* g, bfu* l) {
    __builtin_amdgcn_global_load_lds(
        (const __attribute__((address_space(1))) unsigned int*)(const void*)g,
        (__attribute__((address_space(3))) unsigned int*)(void*)l,
        16, 0, 0);
}

// ---------------------------------------------------------------------------
// Prep (unchanged from R6): 768 blocks, 16KB LDS.
// ---------------------------------------------------------------------------
__global__ __launch_bounds__(256) void prep_kernel(const float* __restrict__ fg,
                                                   bfu* __restrict__ Kpc,
                                                   bfu* __restrict__ Kcp,
                                                   float* __restrict__ S) {
    __shared__ float shbuf[64 * 64];
    int t = threadIdx.x;
    if (blockIdx.x < 512) {
        float* tile  = shbuf;            // [64c][32p] stride 33
        float* rnorm = shbuf + 64 * 33;
        int b  = blockIdx.x >> 7;
        int p0 = (blockIdx.x & 127) << 5;
        const float* src = fg + (size_t)b * Cn * Pn + p0;
        #pragma unroll
        for (int i = 0; i < 8; ++i) {
            int idx = i * 256 + t;
            int c = idx >> 5, p = idx & 31;
            tile[c * 33 + p] = src[(size_t)c * Pn + p];
        }
        __syncthreads();
        if (t < 32) {
            float ss = 0.f;
            #pragma unroll
            for (int c = 0; c < 64; ++c) { float v = tile[c * 33 + t]; ss += v * v; }
            rnorm[t] = 1.0f / (sqrtf(ss) + 1e-8f);
        }
        __syncthreads();
        bfu* dpc = Kpc + ((size_t)b * Pn + p0) * Cn;
        #pragma unroll
        for (int i = 0; i < 8; ++i) {
            int idx = i * 256 + t;
            int p = idx >> 6, c = idx & 63;
            dpc[(size_t)p * Cn + c] = f2bf(tile[c * 33 + p] * rnorm[p]);
        }
        bfu* dcp = Kcp + (size_t)b * Cn * Pn + p0;
        #pragma unroll
        for (int i = 0; i < 8; ++i) {
            int idx = i * 256 + t;
            int c = idx >> 5, p = idx & 31;
            dcp[(size_t)c * Pn + p] = f2bf(tile[c * 33 + p] * rnorm[p]);
        }
    } else {
        float (*pl)[64] = (float(*)[64])shbuf;
        int bc = blockIdx.x - 512;
        const float* src = fg + (size_t)bc * Pn;
        float*       dst = S  + (size_t)bc * Pn;
        #pragma unroll
        for (int i = 0; i < 16; ++i) {
            int idx = i * 256 + t;
            pl[idx >> 6][idx & 63] = src[idx];
        }
        __syncthreads();
        #pragma unroll
        for (int i = 0; i < 16; ++i) {
            int idx = i * 256 + t;
            int h = idx >> 6, w = idx & 63;
            float s = 0.f;
            #pragma unroll
            for (int dh = -1; dh <= 1; ++dh) {
                int hh = h + dh;
                if (hh < 0 || hh >= 64) continue;
                #pragma unroll
                for (int dw = -1; dw <= 1; ++dw) {
                    int ww = w + dw;
                    if (ww < 0 || ww >= 64) continue;
                    s += pl[hh][ww];
                }
            }
            dst[idx] = s * LOG2E;
        }
    }
}

// ---------------------------------------------------------------------------
// Flash: out[:,q] = K^T exp2(K·S'_q)/l_q.  512 thr (8 waves), QT=32, 1 barrier/iter.
//   score: wave w owns p-rows [16w,16w+16); Kpc LDS-staged (dbuf, DMA).
//   accum: wave w = (c-half cw=w&1, K-quarter kq=w>>1); A-frags gathered from
//          GLOBAL Kcp (L2-resident), B-frags from double-buffered El.
//   K-quarter partials combined in the epilogue via LDS overlay.
// LDS: Kpc dbuf 32K | Sl 4K | El dbuf 16K  = 52 KB  -> 2 blocks/CU, 16 waves/CU.
// ---------------------------------------------------------------------------
__global__ __launch_bounds__(512, 4) void flash_kernel(const bfu* __restrict__ Kpc,
                                                       const bfu* __restrict__ Kcp,
                                                       const float* __restrict__ S,
                                                       float* __restrict__ out) {
    // bfu units: Kpc buf0 [0,8192) buf1 [8192,16384) | Sl [16384,18432)
    //            El buf0 [18432,22528) buf1 [22528,26624)
    __shared__ __align__(16) bfu smem[26624];
    __shared__ float wredl[8][QT];
    bfu* Sl = smem + 16384;

    int b  = blockIdx.x >> 7;
    int q0 = (blockIdx.x & 127) * QT;
    int t  = threadIdx.x;
    int w = t >> 6, l = t & 63, lq = l & 15, quad = l >> 4;
    int cw = w & 1;           // accum c-half: rows [32cw, 32cw+32)
    int kq = w >> 1;          // accum K-quarter: p-offset 32*kq within PBK

    const float* Sg  = S   + (size_t)b * Cn * Pn;
    const bfu*   gpc = Kpc + (size_t)b * Pn * Cn;
    const bfu*   gcp = Kcp + (size_t)b * Cn * Pn;

    // Sl[q][c] = bf16(Sg[c][q0+q]) (S pre-scaled by log2e), XOR-swizzled
    {
        int c = t >> 3, qq = (t & 7) * 4;
        const float* sp = &Sg[(size_t)c * Pn + q0 + qq];
        float4 v0 = *(const float4*)sp;
        float vv[4] = {v0.x, v0.y, v0.z, v0.w};
        int ch = c >> 3, cl = c & 7;
        #pragma unroll
        for (int i = 0; i < 4; ++i) {
            int row = qq + i;
            Sl[row * 64 + ((ch ^ (row & 7)) << 3) + cl] = f2bf(vv[i]);
        }
    }

    // stage K(0)->buf0 and K(1)->buf1 (drained by the barrier below)
    #pragma unroll
    for (int pb0 = 0; pb0 < 2; ++pb0) {
        const bfu* gsrc = gpc + (size_t)pb0 * PBK * Cn;
        #pragma unroll
        for (int j = 0; j < 2; ++j) {
            int g = j * 8 + w;
            int ci = g * 64 + l;
            int row = ci >> 3, chp = ci & 7;
            async_load16(gsrc + (size_t)row * Cn + ((chp ^ (row & 7)) << 3),
                         smem + pb0 * 8192 + g * 512);
        }
    }
    __syncthreads();   // Sl visible + K(0),K(1) DMA drained

    // hoist S B-frags: B[k=c][n=q], n=lq(+16nt), k=quad*8+j (+32ks)
    short8 bs[2][2];
    #pragma unroll
    for (int nt = 0; nt < 2; ++nt)
        #pragma unroll
        for (int ks = 0; ks < 2; ++ks) {
            int row = nt * 16 + lq;
            bs[nt][ks] = *(const short8*)&Sl[row * 64 + (((ks * 4 + quad) ^ (lq & 7)) << 3)];
        }

    float4v o[2][2];   // [ct][nt], c = 32cw+16ct+quad*4+r, q = 16nt+lq  (K-quarter partial)
    #pragma unroll
    for (int ct = 0; ct < 2; ++ct)
        #pragma unroll
        for (int nt = 0; nt < 2; ++nt) o[ct][nt] = (float4v){0.f, 0.f, 0.f, 0.f};
    float lacc[2] = {0.f, 0.f};

    for (int pb = 0; pb < NITER; ++pb) {
        bfu* KpcC = smem + (pb & 1) * 8192;
        bfu* ElC  = smem + 18432 + (pb & 1) * 4096;

        // ---- accum A-frag gather from GLOBAL Kcp (used after the barrier) ----
        float4 akr[2];
        #pragma unroll
        for (int ct = 0; ct < 2; ++ct)
            akr[ct] = *(const float4*)&gcp[(size_t)(32 * cw + 16 * ct + lq) * Pn +
                                           pb * PBK + 32 * kq + quad * 8];

        // ---- score GEMM: wave w owns p rows [16w, 16w+16) ----
        short8 af[2];
        #pragma unroll
        for (int ks = 0; ks < 2; ++ks) {
            int row = w * 16 + lq;
            af[ks] = *(const short8*)&KpcC[row * 64 + (((ks * 4 + quad) ^ (lq & 7)) << 3)];
        }
        float4v sc[2];
        #pragma unroll
        for (int nt = 0; nt < 2; ++nt) {
            float4v acc = (float4v){0.f, 0.f, 0.f, 0.f};
            acc = __builtin_amdgcn_mfma_f32_16x16x32_bf16(af[0], bs[nt][0], acc, 0, 0, 0);
            acc = __builtin_amdgcn_mfma_f32_16x16x32_bf16(af[1], bs[nt][1], acc, 0, 0, 0);
            sc[nt] = acc;
        }

        // ---- exp2 + per-lane denominator + El pack (bf16) ----
        // lane holds q = 16nt+lq, p = 16w + 4quad + r
        #pragma unroll
        for (int nt = 0; nt < 2; ++nt) {
            int row = nt * 16 + lq;
            float e0 = __builtin_amdgcn_exp2f(sc[nt][0]);
            float e1 = __builtin_amdgcn_exp2f(sc[nt][1]);
            float e2 = __builtin_amdgcn_exp2f(sc[nt][2]);
            float e3 = __builtin_amdgcn_exp2f(sc[nt][3]);
            lacc[nt] += (e0 + e1) + (e2 + e3);
            __hip_bfloat162 h01 = __float22bfloat162_rn(make_float2(e0, e1));
            __hip_bfloat162 h23 = __float22bfloat162_rn(make_float2(e2, e3));
            uint2 pk = make_uint2(*(unsigned*)&h01, *(unsigned*)&h23);
            int col = w * 16 + quad * 4;
            int ch = (col >> 3) ^ (row & 15), cl = col & 7;
            *(uint2*)&ElC[row * PBK + ch * 8 + cl] = pk;
        }

        __syncthreads();   // El(pb) visible; Kpc(pb+1) DMA drained; score(pb) done on KpcC

        // ---- issue DMA for K(pb+2) into KpcC (all waves done reading it) ----
        if (pb + 2 < NITER) {
            const bfu* gsrc = gpc + (size_t)(pb + 2) * PBK * Cn;
            #pragma unroll
            for (int j = 0; j < 2; ++j) {
                int g = j * 8 + w;
                int ci = g * 64 + l;
                int row = ci >> 3, chp = ci & 7;
                async_load16(gsrc + (size_t)row * Cn + ((chp ^ (row & 7)) << 3),
                             KpcC + g * 512);
            }
        }

        // ---- accum GEMM: o[ct][nt] += Kcp(c-rows) · El over p [32kq,32kq+32) ----
        #pragma unroll
        for (int ct = 0; ct < 2; ++ct) {
            short8 ak = *(short8*)&akr[ct];
            #pragma unroll
            for (int nt = 0; nt < 2; ++nt) {
                int rowB = nt * 16 + lq;
                short8 bk = *(const short8*)&ElC[rowB * PBK + (((4 * kq + quad) ^ (rowB & 15)) << 3)];
                o[ct][nt] = __builtin_amdgcn_mfma_f32_16x16x32_bf16(ak, bk, o[ct][nt], 0, 0, 0);
            }
        }
        // no end barrier: next iter writes the other El buffer; KpcC rewrite
        // is the DMA issued above, which every wave issued after the barrier.
    }

    // ---- denominator: quad-reduce then cross-wave sum ----
    #pragma unroll
    for (int nt = 0; nt < 2; ++nt) {
        lacc[nt] += __shfl_xor(lacc[nt], 16);
        lacc[nt] += __shfl_xor(lacc[nt], 32);
    }
    if (quad == 0) { wredl[w][lq] = lacc[0]; wredl[w][16 + lq] = lacc[1]; }

    // ---- combine K-quarter partials via LDS overlay ----
    float* Ol = (float*)smem;   // [4kq][64c][33] fp32 = 33792 B < 53248 B region
    __syncthreads();            // all accum reads of El done; Kpc/Sl/El dead
    #pragma unroll
    for (int ct = 0; ct < 2; ++ct)
        #pragma unroll
        for (int nt = 0; nt < 2; ++nt)
            #pragma unroll
            for (int r = 0; r < 4; ++r)
                Ol[(kq * 64 + cw * 32 + ct * 16 + quad * 4 + r) * 33 + nt * 16 + lq] = o[ct][nt][r];
    __syncthreads();
    float* og = out + (size_t)b * Cn * Pn;
    #pragma unroll
    for (int i = 0; i < 4; ++i) {
        int idx = i * 512 + t;
        int c = idx >> 5, q = idx & 31;
        float lsum = ((wredl[0][q] + wredl[1][q]) + (wredl[2][q] + wredl[3][q])) +
                     ((wredl[4][q] + wredl[5][q]) + (wredl[6][q] + wredl[7][q]));
        float v = ((Ol[c * 33 + q] + Ol[(64 + c) * 33 + q]) +
                   (Ol[(128 + c) * 33 + q] + Ol[(192 + c) * 33 + q])) / lsum;
        og[(size_t)c * Pn + q0 + q] = v;
    }
}

// ---------------------------------------------------------------------------
extern "C" void kernel_launch(void* const* d_in, const int* in_sizes, int n_in,
                              void* d_out, int out_size, void* d_ws, size_t ws_size,
                              hipStream_t stream) {
    const float* fg = (const float*)d_in[0];
    float* out = (float*)d_out;
    bfu*   Kpc = (bfu*)d_ws;                               // 2 MB  bf16 [B][P][C]
    bfu*   Kcp = Kpc + (size_t)Bn * Pn * Cn;               // 2 MB  bf16 [B][C][P]
    float* S   = (float*)(Kcp + (size_t)Bn * Pn * Cn);     // 4 MB  fp32 [B][C][P] (pre-scaled by log2e)

    prep_kernel <<<768, 256, 0, stream>>>(fg, Kpc, Kcp, S);
    flash_kernel<<<Bn * 128, 512, 0, stream>>>(Kpc, Kcp, S, out);
}

// Round 11
// 105.847 us; speedup vs baseline: 1.0118x; 1.0118x over previous
//
#include <hip/hip_runtime.h>
#include <hip/hip_bf16.h>
#include <math.h>

#define Bn 4
#define Cn 64
#define Pn 4096   // 64*64
#define QT 32     // q-tile per block
#define PBK 128   // p-block per flash iteration
#define NITER (Pn / PBK)
#define LOG2E 1.4426950408889634f

typedef __attribute__((ext_vector_type(8))) short short8;   // 8 bf16 (MFMA K=32 A/B frag)
typedef __attribute__((ext_vector_type(4))) short short4v;  // 4 bf16 (MFMA K=16 A/B frag)
typedef __attribute__((ext_vector_type(4))) float float4v;  // MFMA C/D frag
typedef unsigned short bfu;

__device__ __forceinline__ bfu f2bf(float x) {
    unsigned u = __float_as_uint(x);
    u = (u + 0x7fffu + ((u >> 16) & 1u)) >> 16;   // RNE; inputs finite
    return (bfu)u;
}

// async global->LDS DMA, 16B per lane; GLOBAL address is PER-LANE, LDS dest =
// wave-uniform base + lane*16  (R10 bug: passed uniform global addr)
__device__ __forceinline__ void async_load16(const bfu* g, bfu* l) {
    __builtin_amdgcn_global_load_lds(
        (const __attribute__((address_space(1))) unsigned int*)(const void*)g,
        (__attribute__((address_space(3))) unsigned int*)(void*)l,
        16, 0, 0);
}

// ---------------------------------------------------------------------------
// Prep: 768 blocks, 16KB LDS.
//   blocks [0,512):   knorm -> bf16 Kpc [B][P][C]  and tiled Kcp2 [B][P/16][C][16p]
//   blocks [512,768): 3x3 zero-padded box-sum * log2(e) -> S [B][C][P]
// ---------------------------------------------------------------------------
__global__ __launch_bounds__(256) void prep_kernel(const float* __restrict__ fg,
                                                   bfu* __restrict__ Kpc,
                                                   bfu* __restrict__ Kcp2,
                                                   float* __restrict__ S) {
    __shared__ float shbuf[64 * 64];
    int t = threadIdx.x;
    if (blockIdx.x < 512) {
        float* tile  = shbuf;            // [64c][32p] stride 33
        float* rnorm = shbuf + 64 * 33;
        int b  = blockIdx.x >> 7;
        int p0 = (blockIdx.x & 127) << 5;
        const float* src = fg + (size_t)b * Cn * Pn + p0;
        #pragma unroll
        for (int i = 0; i < 8; ++i) {
            int idx = i * 256 + t;
            int c = idx >> 5, p = idx & 31;
            tile[c * 33 + p] = src[(size_t)c * Pn + p];
        }
        __syncthreads();
        if (t < 32) {
            float ss = 0.f;
            #pragma unroll
            for (int c = 0; c < 64; ++c) { float v = tile[c * 33 + t]; ss += v * v; }
            rnorm[t] = 1.0f / (sqrtf(ss) + 1e-8f);
        }
        __syncthreads();
        bfu* dpc = Kpc + ((size_t)b * Pn + p0) * Cn;
        #pragma unroll
        for (int i = 0; i < 8; ++i) {
            int idx = i * 256 + t;
            int p = idx >> 6, c = idx & 63;
            dpc[(size_t)p * Cn + c] = f2bf(tile[c * 33 + p] * rnorm[p]);
        }
        // tiled transpose layout: Kcp2[b][pt][c][pl], pt = p>>4, pl = p&15
        bfu* d2 = Kcp2 + ((size_t)b * 256 + (p0 >> 4)) * 1024;
        #pragma unroll
        for (int i = 0; i < 8; ++i) {
            int idx = i * 256 + t;
            int c = idx >> 5, p = idx & 31;
            d2[(size_t)(p >> 4) * 1024 + c * 16 + (p & 15)] =
                f2bf(tile[c * 33 + p] * rnorm[p]);
        }
    } else {
        float (*pl)[64] = (float(*)[64])shbuf;
        int bc = blockIdx.x - 512;
        const float* src = fg + (size_t)bc * Pn;
        float*       dst = S  + (size_t)bc * Pn;
        #pragma unroll
        for (int i = 0; i < 16; ++i) {
            int idx = i * 256 + t;
            pl[idx >> 6][idx & 63] = src[idx];
        }
        __syncthreads();
        #pragma unroll
        for (int i = 0; i < 16; ++i) {
            int idx = i * 256 + t;
            int h = idx >> 6, w = idx & 63;
            float s = 0.f;
            #pragma unroll
            for (int dh = -1; dh <= 1; ++dh) {
                int hh = h + dh;
                if (hh < 0 || hh >= 64) continue;
                #pragma unroll
                for (int dw = -1; dw <= 1; ++dw) {
                    int ww = w + dw;
                    if (ww < 0 || ww >= 64) continue;
                    s += pl[hh][ww];
                }
            }
            dst[idx] = s * LOG2E;
        }
    }
}

// ---------------------------------------------------------------------------
// Flash, barrier-free K-loop. 512 thr (8 waves), QT=32.
// Wave w owns p-rows [16w,16w+16) of each 128-p block end-to-end:
//   score: A = global Kpc rows (dwordx4 gather), B = hoisted S frags (K=32 MFMA)
//   exp'd scores stay in REGISTERS as A-frags of K=16 MFMAs (C-layout == A-layout)
//   accum B: wave-private 2KB Kcp2 tile, self-DMA'd (double-buffered, no barrier)
// Cross-wave combine (o' partials + denominators) once after the loop.
// ---------------------------------------------------------------------------
__global__ __launch_bounds__(512, 4) void flash_kernel(const bfu* __restrict__ Kpc,
                                                       const bfu* __restrict__ Kcp2,
                                                       const float* __restrict__ S,
                                                       float* __restrict__ out) {
    // bfu units: Kcp2 tiles dbuf [0,16384): [buf][wave][1024] | Sl [16384,18432)
    __shared__ __align__(16) bfu smem[18432];
    __shared__ float wredl[8][QT];
    bfu* Sl = smem + 16384;

    int b  = blockIdx.x >> 7;
    int q0 = (blockIdx.x & 127) * QT;
    int t  = threadIdx.x;
    int w = t >> 6, l = t & 63, lq = l & 15, quad = l >> 4;

    const float* Sg  = S    + (size_t)b * Cn * Pn;
    const bfu*   gpc = Kpc  + (size_t)b * Pn * Cn;
    const bfu*   gt  = Kcp2 + (size_t)b * 256 * 1024;   // [pt][c][pl]

    // Sl[q][c] = bf16(Sg[c][q0+q]) (S pre-scaled by log2e), XOR-swizzled
    {
        int c = t >> 3, qq = (t & 7) * 4;
        const float* sp = &Sg[(size_t)c * Pn + q0 + qq];
        float4 v0 = *(const float4*)sp;
        float vv[4] = {v0.x, v0.y, v0.z, v0.w};
        int ch = c >> 3, cl = c & 7;
        #pragma unroll
        for (int i = 0; i < 4; ++i) {
            int row = qq + i;
            Sl[row * 64 + ((ch ^ (row & 7)) << 3) + cl] = f2bf(vv[i]);
        }
    }

    // DMA tile(pt=w) for pb=0 into buf0 (wave-private); PER-LANE src offset l*8
    {
        const bfu* src = gt + (size_t)w * 1024 + l * 8;
        bfu* dst = smem + w * 1024;
        async_load16(src, dst);
        async_load16(src + 512, dst + 512);
    }
    __syncthreads();   // Sl visible; DMA(0) drained (vmcnt(0) at barrier)

    // hoist S B-frags: B[k=c][n=q], n=lq(+16nt), k=quad*8+j (+32ks)
    short8 bs[2][2];
    #pragma unroll
    for (int nt = 0; nt < 2; ++nt)
        #pragma unroll
        for (int ks = 0; ks < 2; ++ks) {
            int row = nt * 16 + lq;
            bs[nt][ks] = *(const short8*)&Sl[row * 64 + (((ks * 4 + quad) ^ (lq & 7)) << 3)];
        }

    float4v o[2][4];   // [nt][cb]: q = 16nt+4quad+r, c = 16cb+lq (wave-private p-partial)
    #pragma unroll
    for (int nt = 0; nt < 2; ++nt)
        #pragma unroll
        for (int cb = 0; cb < 4; ++cb) o[nt][cb] = (float4v){0.f, 0.f, 0.f, 0.f};
    float lacc[2] = {0.f, 0.f};

    for (int pb = 0; pb < NITER; ++pb) {
        bfu* tile = smem + (pb & 1) * 8192 + w * 1024;

        // ---- score A-frags from global Kpc (rows p = pb*128+16w+lq) ----
        const bfu* ap = gpc + ((size_t)pb * PBK + 16 * w + lq) * Cn + quad * 8;
        float4 a0 = *(const float4*)ap;          // k = quad*8+j (c 0..31)
        float4 a1 = *(const float4*)(ap + 32);   // k (c 32..63)

        // ---- self-DMA next Kcp2 tile (pt = (pb+1)*8+w) into other buffer ----
        if (pb + 1 < NITER) {
            const bfu* src = gt + ((size_t)(pb + 1) * 8 + w) * 1024 + l * 8;
            bfu* dst = smem + ((pb + 1) & 1) * 8192 + w * 1024;
            async_load16(src, dst);
            async_load16(src + 512, dst + 512);
        }

        // ---- score GEMM (K=32): D[m=p][n=q] ----
        short8 af0 = *(short8*)&a0, af1 = *(short8*)&a1;
        float4v sc[2];
        #pragma unroll
        for (int nt = 0; nt < 2; ++nt) {
            float4v acc = (float4v){0.f, 0.f, 0.f, 0.f};
            acc = __builtin_amdgcn_mfma_f32_16x16x32_bf16(af0, bs[nt][0], acc, 0, 0, 0);
            acc = __builtin_amdgcn_mfma_f32_16x16x32_bf16(af1, bs[nt][1], acc, 0, 0, 0);
            sc[nt] = acc;
        }

        // ---- exp2 + denominator; pack E directly as K=16 A-frags ----
        // lane holds q = 16nt+lq (col), p_loc = 4quad+r (row) == A[m=q][k=4quad+j]
        short4v epk[2];
        #pragma unroll
        for (int nt = 0; nt < 2; ++nt) {
            float e0 = __builtin_amdgcn_exp2f(sc[nt][0]);
            float e1 = __builtin_amdgcn_exp2f(sc[nt][1]);
            float e2 = __builtin_amdgcn_exp2f(sc[nt][2]);
            float e3 = __builtin_amdgcn_exp2f(sc[nt][3]);
            lacc[nt] += (e0 + e1) + (e2 + e3);
            short4v ep = {(short)f2bf(e0), (short)f2bf(e1), (short)f2bf(e2), (short)f2bf(e3)};
            epk[nt] = ep;
        }

        // guard: DMA(pb) (older than this iter's af loads) must be drained before
        // tile ds_reads. vmcnt(2) leaves only the 2 just-issued DMA(pb+1) in flight.
        // sched_barrier pins the ds_reads below the waitcnt (no register dep exists).
        __builtin_amdgcn_s_waitcnt(0x0F72);
        __builtin_amdgcn_sched_barrier(0);

        // ---- accum GEMM (K=16): o'[q][c] += E · Kcp2tile ----
        #pragma unroll
        for (int cb = 0; cb < 4; ++cb) {
            // B[k=p_loc][n=c]: lane n=lq -> c=16cb+lq, k=4quad+j -> 8B contiguous
            short4v kb = *(const short4v*)&tile[(16 * cb + lq) * 16 + quad * 4];
            o[0][cb] = __builtin_amdgcn_mfma_f32_16x16x16bf16_1k(epk[0], kb, o[0][cb], 0, 0, 0);
            o[1][cb] = __builtin_amdgcn_mfma_f32_16x16x16bf16_1k(epk[1], kb, o[1][cb], 0, 0, 0);
        }
        // no barrier: tile is wave-private; E never touches LDS.
    }

    // ---- denominator: quad-reduce then stash per wave ----
    #pragma unroll
    for (int nt = 0; nt < 2; ++nt) {
        lacc[nt] += __shfl_xor(lacc[nt], 16);
        lacc[nt] += __shfl_xor(lacc[nt], 32);
    }
    if (quad == 0) { wredl[w][lq] = lacc[0]; wredl[w][16 + lq] = lacc[1]; }

    // ---- cross-wave combine via LDS overlay (2 rounds in 34KB) ----
    float* Ol = (float*)smem;   // [4][32 q][66] fp32 = 33792 B < 36864 B
    __syncthreads();            // all waves done with tiles/Sl; wredl visible
    if (w < 4) {
        #pragma unroll
        for (int nt = 0; nt < 2; ++nt)
            #pragma unroll
            for (int cb = 0; cb < 4; ++cb)
                #pragma unroll
                for (int r = 0; r < 4; ++r)
                    Ol[(w * 32 + nt * 16 + quad * 4 + r) * 66 + cb * 16 + lq] = o[nt][cb][r];
    }
    __syncthreads();
    if (w >= 4) {
        #pragma unroll
        for (int nt = 0; nt < 2; ++nt)
            #pragma unroll
            for (int cb = 0; cb < 4; ++cb)
                #pragma unroll
                for (int r = 0; r < 4; ++r)
                    Ol[((w - 4) * 32 + nt * 16 + quad * 4 + r) * 66 + cb * 16 + lq] += o[nt][cb][r];
    }
    __syncthreads();

    // ---- final: out[c][q0+q] = sum of 4 buffers / l_q ----
    float* og = out + (size_t)b * Cn * Pn;
    #pragma unroll
    for (int i = 0; i < 4; ++i) {
        int idx = i * 512 + t;
        int c = idx >> 5, q = idx & 31;
        float lsum = ((wredl[0][q] + wredl[1][q]) + (wredl[2][q] + wredl[3][q])) +
                     ((wredl[4][q] + wredl[5][q]) + (wredl[6][q] + wredl[7][q]));
        float v = ((Ol[q * 66 + c] + Ol[(32 + q) * 66 + c]) +
                   (Ol[(64 + q) * 66 + c] + Ol[(96 + q) * 66 + c])) / lsum;
        og[(size_t)c * Pn + q0 + q] = v;
    }
}

// ---------------------------------------------------------------------------
extern "C" void kernel_launch(void* const* d_in, const int* in_sizes, int n_in,
                              void* d_out, int out_size, void* d_ws, size_t ws_size,
                              hipStream_t stream) {
    const float* fg = (const float*)d_in[0];
    float* out = (float*)d_out;
    bfu*   Kpc  = (bfu*)d_ws;                              // 2 MB  bf16 [B][P][C]
    bfu*   Kcp2 = Kpc + (size_t)Bn * Pn * Cn;              // 2 MB  bf16 [B][P/16][C][16]
    float* S    = (float*)(Kcp2 + (size_t)Bn * Pn * Cn);   // 4 MB  fp32 [B][C][P] (pre-scaled by log2e)

    prep_kernel <<<768, 256, 0, stream>>>(fg, Kpc, Kcp2, S);
    flash_kernel<<<Bn * 128, 512, 0, stream>>>(Kpc, Kcp2, S, out);
}

// Round 12
// 95.983 us; speedup vs baseline: 1.1158x; 1.1028x over previous
//
#include <hip/hip_runtime.h>
#include <hip/hip_bf16.h>
#include <math.h>

#define Bn 4
#define Cn 64
#define Pn 4096   // 64*64
#define QT 64     // q-tile per block (R12: doubled)
#define PBK 128   // p-block per flash iteration
#define NITER (Pn / PBK)
#define LOG2E 1.4426950408889634f

typedef __attribute__((ext_vector_type(8))) short short8;   // 8 bf16 (MFMA K=32 A/B frag)
typedef __attribute__((ext_vector_type(4))) short short4v;  // 4 bf16 (MFMA K=16 A/B frag)
typedef __attribute__((ext_vector_type(4))) float float4v;  // MFMA C/D frag
typedef unsigned short bfu;

__device__ __forceinline__ bfu f2bf(float x) {
    unsigned u = __float_as_uint(x);
    u = (u + 0x7fffu + ((u >> 16) & 1u)) >> 16;   // RNE; inputs finite
    return (bfu)u;
}

// async global->LDS DMA, 16B per lane; PER-LANE global addr, LDS dest = base + lane*16
__device__ __forceinline__ void async_load16(const bfu* g, bfu* l) {
    __builtin_amdgcn_global_load_lds(
        (const __attribute__((address_space(1))) unsigned int*)(const void*)g,
        (__attribute__((address_space(3))) unsigned int*)(void*)l,
        16, 0, 0);
}

// ---------------------------------------------------------------------------
// Prep (unchanged from R11): 768 blocks, 16KB LDS.
//   blocks [0,512):   knorm -> bf16 Kpc [B][P][C]  and tiled Kcp2 [B][P/16][C][16p]
//   blocks [512,768): 3x3 zero-padded box-sum * log2(e) -> S [B][C][P]
// ---------------------------------------------------------------------------
__global__ __launch_bounds__(256) void prep_kernel(const float* __restrict__ fg,
                                                   bfu* __restrict__ Kpc,
                                                   bfu* __restrict__ Kcp2,
                                                   float* __restrict__ S) {
    __shared__ float shbuf[64 * 64];
    int t = threadIdx.x;
    if (blockIdx.x < 512) {
        float* tile  = shbuf;            // [64c][32p] stride 33
        float* rnorm = shbuf + 64 * 33;
        int b  = blockIdx.x >> 7;
        int p0 = (blockIdx.x & 127) << 5;
        const float* src = fg + (size_t)b * Cn * Pn + p0;
        #pragma unroll
        for (int i = 0; i < 8; ++i) {
            int idx = i * 256 + t;
            int c = idx >> 5, p = idx & 31;
            tile[c * 33 + p] = src[(size_t)c * Pn + p];
        }
        __syncthreads();
        if (t < 32) {
            float ss = 0.f;
            #pragma unroll
            for (int c = 0; c < 64; ++c) { float v = tile[c * 33 + t]; ss += v * v; }
            rnorm[t] = 1.0f / (sqrtf(ss) + 1e-8f);
        }
        __syncthreads();
        bfu* dpc = Kpc + ((size_t)b * Pn + p0) * Cn;
        #pragma unroll
        for (int i = 0; i < 8; ++i) {
            int idx = i * 256 + t;
            int p = idx >> 6, c = idx & 63;
            dpc[(size_t)p * Cn + c] = f2bf(tile[c * 33 + p] * rnorm[p]);
        }
        // tiled transpose layout: Kcp2[b][pt][c][pl], pt = p>>4, pl = p&15
        bfu* d2 = Kcp2 + ((size_t)b * 256 + (p0 >> 4)) * 1024;
        #pragma unroll
        for (int i = 0; i < 8; ++i) {
            int idx = i * 256 + t;
            int c = idx >> 5, p = idx & 31;
            d2[(size_t)(p >> 4) * 1024 + c * 16 + (p & 15)] =
                f2bf(tile[c * 33 + p] * rnorm[p]);
        }
    } else {
        float (*pl)[64] = (float(*)[64])shbuf;
        int bc = blockIdx.x - 512;
        const float* src = fg + (size_t)bc * Pn;
        float*       dst = S  + (size_t)bc * Pn;
        #pragma unroll
        for (int i = 0; i < 16; ++i) {
            int idx = i * 256 + t;
            pl[idx >> 6][idx & 63] = src[idx];
        }
        __syncthreads();
        #pragma unroll
        for (int i = 0; i < 16; ++i) {
            int idx = i * 256 + t;
            int h = idx >> 6, w = idx & 63;
            float s = 0.f;
            #pragma unroll
            for (int dh = -1; dh <= 1; ++dh) {
                int hh = h + dh;
                if (hh < 0 || hh >= 64) continue;
                #pragma unroll
                for (int dw = -1; dw <= 1; ++dw) {
                    int ww = w + dw;
                    if (ww < 0 || ww >= 64) continue;
                    s += pl[hh][ww];
                }
            }
            dst[idx] = s * LOG2E;
        }
    }
}

// ---------------------------------------------------------------------------
// Flash, barrier-free K-loop, QT=64. 256 blocks x 512 thr (1 block/CU).
// XCD swizzle: b=(i&7)>>1 -> batch b's blocks land on XCD pair {2b,2b+1},
// keeping the batch's ~2.5MB K working set inside one XCD's 4MB L2.
// Wave w owns p-rows [16w,16w+16) of each 128-p block end-to-end:
//   score: A = global Kpc rows, B = hoisted S frags (K=32 MFMA, 8/iter)
//   exp'd scores -> register K=16 A-frags (C-layout == A-layout)
//   accum: B = wave-private 2KB Kcp2 tile (self-DMA, dbuf); 16 K=16 MFMA/iter
// Cross-wave combine (o partials + denominators) once after the loop.
// ---------------------------------------------------------------------------
__global__ __launch_bounds__(512, 1) void flash_kernel(const bfu* __restrict__ Kpc,
                                                       const bfu* __restrict__ Kcp2,
                                                       const float* __restrict__ S,
                                                       float* __restrict__ out) {
    // bfu units: Kcp2 tiles dbuf [0,16384) ([buf][wave][1024]) | Sl [16384,20480)
    // epilogue overlays everything: Ol fp32 [4][64][66] = 67584 B
    __shared__ __align__(16) bfu smem[33792];
    __shared__ float wredl[8][QT];
    bfu* Sl = smem + 16384;

    int i  = blockIdx.x;
    int b  = (i & 7) >> 1;                       // XCD-pair locality
    int qt = ((i >> 3) << 1) | (i & 1);
    int q0 = qt * QT;
    int t  = threadIdx.x;
    int w = t >> 6, l = t & 63, lq = l & 15, quad = l >> 4;

    const float* Sg  = S    + (size_t)b * Cn * Pn;
    const bfu*   gpc = Kpc  + (size_t)b * Pn * Cn;
    const bfu*   gt  = Kcp2 + (size_t)b * 256 * 1024;   // [pt][c][pl]

    // Sl[q][c] = bf16(Sg[c][q0+q]) (S pre-scaled by log2e), XOR-swizzled rows
    {
        int c = t >> 3, qq = (t & 7) * 8;
        const float* sp = &Sg[(size_t)c * Pn + q0 + qq];
        float4 v0 = *(const float4*)sp;
        float4 v1 = *(const float4*)(sp + 4);
        float vv[8] = {v0.x, v0.y, v0.z, v0.w, v1.x, v1.y, v1.z, v1.w};
        int ch = c >> 3, cl = c & 7;
        #pragma unroll
        for (int k = 0; k < 8; ++k) {
            int row = qq + k;
            Sl[row * 64 + ((ch ^ (row & 7)) << 3) + cl] = f2bf(vv[k]);
        }
    }

    // DMA tile(pt=w) for pb=0 into buf0 (wave-private); per-lane src offset l*8
    {
        const bfu* src = gt + (size_t)w * 1024 + l * 8;
        bfu* dst = smem + w * 1024;
        async_load16(src, dst);
        async_load16(src + 512, dst + 512);
    }
    __syncthreads();   // Sl visible; DMA(0) drained

    // hoist S B-frags: B[k=c][n=q], n=lq(+16nt), k=quad*8+j (+32ks)
    short8 bs[4][2];
    #pragma unroll
    for (int nt = 0; nt < 4; ++nt)
        #pragma unroll
        for (int ks = 0; ks < 2; ++ks) {
            int row = nt * 16 + lq;
            bs[nt][ks] = *(const short8*)&Sl[row * 64 + (((ks * 4 + quad) ^ (lq & 7)) << 3)];
        }

    float4v o[4][4];   // [nt][cb]: q = 16nt+4quad+r, c = 16cb+lq (wave-private p-partial)
    #pragma unroll
    for (int nt = 0; nt < 4; ++nt)
        #pragma unroll
        for (int cb = 0; cb < 4; ++cb) o[nt][cb] = (float4v){0.f, 0.f, 0.f, 0.f};
    float lacc[4] = {0.f, 0.f, 0.f, 0.f};

    for (int pb = 0; pb < NITER; ++pb) {
        bfu* tile = smem + (pb & 1) * 8192 + w * 1024;

        // ---- score A-frags from global Kpc (rows p = pb*128+16w+lq) ----
        const bfu* ap = gpc + ((size_t)pb * PBK + 16 * w + lq) * Cn + quad * 8;
        float4 a0 = *(const float4*)ap;          // k (c 0..31)
        float4 a1 = *(const float4*)(ap + 32);   // k (c 32..63)

        // ---- self-DMA next Kcp2 tile into the other buffer ----
        if (pb + 1 < NITER) {
            const bfu* src = gt + ((size_t)(pb + 1) * 8 + w) * 1024 + l * 8;
            bfu* dst = smem + ((pb + 1) & 1) * 8192 + w * 1024;
            async_load16(src, dst);
            async_load16(src + 512, dst + 512);
        }

        // ---- score GEMM (K=32): D[m=p][n=q], 4 q-subtiles ----
        short8 af0 = *(short8*)&a0, af1 = *(short8*)&a1;
        float4v sc[4];
        #pragma unroll
        for (int nt = 0; nt < 4; ++nt) {
            float4v acc = (float4v){0.f, 0.f, 0.f, 0.f};
            acc = __builtin_amdgcn_mfma_f32_16x16x32_bf16(af0, bs[nt][0], acc, 0, 0, 0);
            acc = __builtin_amdgcn_mfma_f32_16x16x32_bf16(af1, bs[nt][1], acc, 0, 0, 0);
            sc[nt] = acc;
        }

        // ---- exp2 + denominator; pack E directly as K=16 A-frags ----
        short4v epk[4];
        #pragma unroll
        for (int nt = 0; nt < 4; ++nt) {
            float e0 = __builtin_amdgcn_exp2f(sc[nt][0]);
            float e1 = __builtin_amdgcn_exp2f(sc[nt][1]);
            float e2 = __builtin_amdgcn_exp2f(sc[nt][2]);
            float e3 = __builtin_amdgcn_exp2f(sc[nt][3]);
            lacc[nt] += (e0 + e1) + (e2 + e3);
            short4v ep = {(short)f2bf(e0), (short)f2bf(e1), (short)f2bf(e2), (short)f2bf(e3)};
            epk[nt] = ep;
        }

        // guard: DMA(pb) must be drained before tile ds_reads (vmcnt(2) leaves
        // only the 2 just-issued DMA(pb+1) in flight); pin ds_reads below it.
        __builtin_amdgcn_s_waitcnt(0x0F72);
        __builtin_amdgcn_sched_barrier(0);

        // ---- accum GEMM (K=16): o'[q][c] += E · Kcp2tile ----
        #pragma unroll
        for (int cb = 0; cb < 4; ++cb) {
            short4v kb = *(const short4v*)&tile[(16 * cb + lq) * 16 + quad * 4];
            #pragma unroll
            for (int nt = 0; nt < 4; ++nt)
                o[nt][cb] = __builtin_amdgcn_mfma_f32_16x16x16bf16_1k(epk[nt], kb, o[nt][cb], 0, 0, 0);
        }
        // no barrier: tile is wave-private; E never touches LDS.
    }

    // ---- denominator: quad-reduce then stash per wave ----
    #pragma unroll
    for (int nt = 0; nt < 4; ++nt) {
        lacc[nt] += __shfl_xor(lacc[nt], 16);
        lacc[nt] += __shfl_xor(lacc[nt], 32);
    }
    if (quad == 0)
        #pragma unroll
        for (int nt = 0; nt < 4; ++nt) wredl[w][nt * 16 + lq] = lacc[nt];

    // ---- cross-wave combine via LDS overlay (2 rounds) ----
    float* Ol = (float*)smem;   // [4][64 c][66] fp32 = 67584 B
    __syncthreads();            // all tile/Sl reads done; wredl visible
    if (w < 4) {
        #pragma unroll
        for (int nt = 0; nt < 4; ++nt)
            #pragma unroll
            for (int cb = 0; cb < 4; ++cb)
                #pragma unroll
                for (int r = 0; r < 4; ++r)
                    Ol[(w * 64 + 16 * cb + lq) * 66 + nt * 16 + quad * 4 + r] = o[nt][cb][r];
    }
    __syncthreads();
    if (w >= 4) {
        #pragma unroll
        for (int nt = 0; nt < 4; ++nt)
            #pragma unroll
            for (int cb = 0; cb < 4; ++cb)
                #pragma unroll
                for (int r = 0; r < 4; ++r)
                    Ol[((w - 4) * 64 + 16 * cb + lq) * 66 + nt * 16 + quad * 4 + r] += o[nt][cb][r];
    }
    __syncthreads();

    // ---- final: out[c][q0+q] = sum of 4 buffers / l_q ----
    float* og = out + (size_t)b * Cn * Pn;
    #pragma unroll
    for (int k = 0; k < 8; ++k) {
        int idx = k * 512 + t;
        int c = idx >> 6, q = idx & 63;
        float lsum = ((wredl[0][q] + wredl[1][q]) + (wredl[2][q] + wredl[3][q])) +
                     ((wredl[4][q] + wredl[5][q]) + (wredl[6][q] + wredl[7][q]));
        float v = ((Ol[c * 66 + q] + Ol[(64 + c) * 66 + q]) +
                   (Ol[(128 + c) * 66 + q] + Ol[(192 + c) * 66 + q])) / lsum;
        og[(size_t)c * Pn + q0 + q] = v;
    }
}

// ---------------------------------------------------------------------------
extern "C" void kernel_launch(void* const* d_in, const int* in_sizes, int n_in,
                              void* d_out, int out_size, void* d_ws, size_t ws_size,
                              hipStream_t stream) {
    const float* fg = (const float*)d_in[0];
    float* out = (float*)d_out;
    bfu*   Kpc  = (bfu*)d_ws;                              // 2 MB  bf16 [B][P][C]
    bfu*   Kcp2 = Kpc + (size_t)Bn * Pn * Cn;              // 2 MB  bf16 [B][P/16][C][16]
    float* S    = (float*)(Kcp2 + (size_t)Bn * Pn * Cn);   // 4 MB  fp32 [B][C][P] (pre-scaled by log2e)

    prep_kernel <<<768, 256, 0, stream>>>(fg, Kpc, Kcp2, S);
    flash_kernel<<<Bn * 64, 512, 0, stream>>>(Kpc, Kcp2, S, out);
}

// Round 13
// 92.348 us; speedup vs baseline: 1.1597x; 1.0394x over previous
//
#include <hip/hip_runtime.h>
#include <hip/hip_bf16.h>
#include <math.h>

#define Bn 4
#define Cn 64
#define Pn 4096   // 64*64
#define QT 64     // q-tile per block
#define PBK 128   // p-block per flash iteration
#define NITER (Pn / PBK)
#define LOG2E 1.4426950408889634f

typedef __attribute__((ext_vector_type(8))) short short8;   // 8 bf16 (MFMA K=32 A/B frag)
typedef __attribute__((ext_vector_type(4))) short short4v;  // 4 bf16 (MFMA K=16 A/B frag)
typedef __attribute__((ext_vector_type(4))) float float4v;  // MFMA C/D frag
typedef unsigned short bfu;

__device__ __forceinline__ bfu f2bf(float x) {
    unsigned u = __float_as_uint(x);
    u = (u + 0x7fffu + ((u >> 16) & 1u)) >> 16;   // RNE; inputs finite
    return (bfu)u;
}

// ---------------------------------------------------------------------------
// Prep (unchanged from R11/R12): 768 blocks, 16KB LDS.
//   blocks [0,512):   knorm -> bf16 Kpc [B][P][C]  and tiled Kcp2 [B][P/16][C][16p]
//   blocks [512,768): 3x3 zero-padded box-sum * log2(e) -> S [B][C][P]
// ---------------------------------------------------------------------------
__global__ __launch_bounds__(256) void prep_kernel(const float* __restrict__ fg,
                                                   bfu* __restrict__ Kpc,
                                                   bfu* __restrict__ Kcp2,
                                                   float* __restrict__ S) {
    __shared__ float shbuf[64 * 64];
    int t = threadIdx.x;
    if (blockIdx.x < 512) {
        float* tile  = shbuf;            // [64c][32p] stride 33
        float* rnorm = shbuf + 64 * 33;
        int b  = blockIdx.x >> 7;
        int p0 = (blockIdx.x & 127) << 5;
        const float* src = fg + (size_t)b * Cn * Pn + p0;
        #pragma unroll
        for (int i = 0; i < 8; ++i) {
            int idx = i * 256 + t;
            int c = idx >> 5, p = idx & 31;
            tile[c * 33 + p] = src[(size_t)c * Pn + p];
        }
        __syncthreads();
        if (t < 32) {
            float ss = 0.f;
            #pragma unroll
            for (int c = 0; c < 64; ++c) { float v = tile[c * 33 + t]; ss += v * v; }
            rnorm[t] = 1.0f / (sqrtf(ss) + 1e-8f);
        }
        __syncthreads();
        bfu* dpc = Kpc + ((size_t)b * Pn + p0) * Cn;
        #pragma unroll
        for (int i = 0; i < 8; ++i) {
            int idx = i * 256 + t;
            int p = idx >> 6, c = idx & 63;
            dpc[(size_t)p * Cn + c] = f2bf(tile[c * 33 + p] * rnorm[p]);
        }
        // tiled transpose layout: Kcp2[b][pt][c][pl], pt = p>>4, pl = p&15
        bfu* d2 = Kcp2 + ((size_t)b * 256 + (p0 >> 4)) * 1024;
        #pragma unroll
        for (int i = 0; i < 8; ++i) {
            int idx = i * 256 + t;
            int c = idx >> 5, p = idx & 31;
            d2[(size_t)(p >> 4) * 1024 + c * 16 + (p & 15)] =
                f2bf(tile[c * 33 + p] * rnorm[p]);
        }
    } else {
        float (*pl)[64] = (float(*)[64])shbuf;
        int bc = blockIdx.x - 512;
        const float* src = fg + (size_t)bc * Pn;
        float*       dst = S  + (size_t)bc * Pn;
        #pragma unroll
        for (int i = 0; i < 16; ++i) {
            int idx = i * 256 + t;
            pl[idx >> 6][idx & 63] = src[idx];
        }
        __syncthreads();
        #pragma unroll
        for (int i = 0; i < 16; ++i) {
            int idx = i * 256 + t;
            int h = idx >> 6, w = idx & 63;
            float s = 0.f;
            #pragma unroll
            for (int dh = -1; dh <= 1; ++dh) {
                int hh = h + dh;
                if (hh < 0 || hh >= 64) continue;
                #pragma unroll
                for (int dw = -1; dw <= 1; ++dw) {
                    int ww = w + dw;
                    if (ww < 0 || ww >= 64) continue;
                    s += pl[hh][ww];
                }
            }
            dst[idx] = s * LOG2E;
        }
    }
}

// ---------------------------------------------------------------------------
// Flash, ZERO-LDS K-loop (R13). 256 blocks x 512 thr, QT=64, XCD swizzle.
// Wave w owns p-rows [16w,16w+16) of each 128-p block end-to-end:
//   score: A = global Kpc rows (dwordx4), B = hoisted S frags (K=32 MFMA x8)
//   exp'd scores -> register K=16 A-frags (C-layout == A-layout)
//   accum: B = global Kcp2 frags (dwordx2, conflict-free by construction),
//          K=16 MFMA x16; all loads software-prefetched one iteration ahead.
// No LDS, no barriers, no waitcnt tricks inside the loop.
// ---------------------------------------------------------------------------
__global__ __launch_bounds__(512, 1) void flash_kernel(const bfu* __restrict__ Kpc,
                                                       const bfu* __restrict__ Kcp2,
                                                       const float* __restrict__ S,
                                                       float* __restrict__ out) {
    // Sl lives in [0,8192) bfu; epilogue Ol fp32 [4][64][66] overlays all 67.5 KB
    __shared__ __align__(16) bfu smem[33792];
    __shared__ float wredl[8][QT];
    bfu* Sl = smem;

    int i  = blockIdx.x;
    int b  = (i & 7) >> 1;                       // XCD-pair locality
    int qt = ((i >> 3) << 1) | (i & 1);
    int q0 = qt * QT;
    int t  = threadIdx.x;
    int w = t >> 6, l = t & 63, lq = l & 15, quad = l >> 4;

    const float* Sg  = S    + (size_t)b * Cn * Pn;
    const bfu*   gpc = Kpc  + (size_t)b * Pn * Cn;
    const bfu*   gt  = Kcp2 + (size_t)b * 256 * 1024;   // [pt][c][pl]

    // Sl[q][c] = bf16(Sg[c][q0+q]) (S pre-scaled by log2e), XOR-swizzled rows
    {
        int c = t >> 3, qq = (t & 7) * 8;
        const float* sp = &Sg[(size_t)c * Pn + q0 + qq];
        float4 v0 = *(const float4*)sp;
        float4 v1 = *(const float4*)(sp + 4);
        float vv[8] = {v0.x, v0.y, v0.z, v0.w, v1.x, v1.y, v1.z, v1.w};
        int ch = c >> 3, cl = c & 7;
        #pragma unroll
        for (int k = 0; k < 8; ++k) {
            int row = qq + k;
            Sl[row * 64 + ((ch ^ (row & 7)) << 3) + cl] = f2bf(vv[k]);
        }
    }
    __syncthreads();   // Sl visible

    // hoist S B-frags: B[k=c][n=q], n=lq(+16nt), k=quad*8+j (+32ks)
    short8 bs[4][2];
    #pragma unroll
    for (int nt = 0; nt < 4; ++nt)
        #pragma unroll
        for (int ks = 0; ks < 2; ++ks) {
            int row = nt * 16 + lq;
            bs[nt][ks] = *(const short8*)&Sl[row * 64 + (((ks * 4 + quad) ^ (lq & 7)) << 3)];
        }

    float4v o[4][4];   // [nt][cb]: q = 16nt+4quad+r, c = 16cb+lq (wave-private p-partial)
    #pragma unroll
    for (int nt = 0; nt < 4; ++nt)
        #pragma unroll
        for (int cb = 0; cb < 4; ++cb) o[nt][cb] = (float4v){0.f, 0.f, 0.f, 0.f};
    float lacc[4] = {0.f, 0.f, 0.f, 0.f};

    // per-wave global addresses (advance by constants each iteration)
    const bfu* ap = gpc + ((size_t)16 * w + lq) * Cn + quad * 8;           // score A rows
    const bfu* tp = gt + (size_t)w * 1024 + lq * 16 + quad * 4;            // accum B frags

    // prologue: load pb=0 operands
    float4 a0 = *(const float4*)ap;
    float4 a1 = *(const float4*)(ap + 32);
    short4v kb[4];
    #pragma unroll
    for (int cb = 0; cb < 4; ++cb) kb[cb] = *(const short4v*)(tp + cb * 256);

    for (int pb = 0; pb < NITER; ++pb) {
        // ---- prefetch pb+1 operands (independent; compiler issues early) ----
        float4 na0, na1;
        short4v nkb[4];
        if (pb + 1 < NITER) {
            const bfu* apn = ap + (size_t)(pb + 1) * PBK * Cn;
            na0 = *(const float4*)apn;
            na1 = *(const float4*)(apn + 32);
            const bfu* tpn = tp + (size_t)(pb + 1) * 8 * 1024;
            #pragma unroll
            for (int cb = 0; cb < 4; ++cb) nkb[cb] = *(const short4v*)(tpn + cb * 256);
        }

        // ---- score GEMM (K=32): D[m=p][n=q], 4 q-subtiles ----
        short8 af0 = *(short8*)&a0, af1 = *(short8*)&a1;
        float4v sc[4];
        #pragma unroll
        for (int nt = 0; nt < 4; ++nt) {
            float4v acc = (float4v){0.f, 0.f, 0.f, 0.f};
            acc = __builtin_amdgcn_mfma_f32_16x16x32_bf16(af0, bs[nt][0], acc, 0, 0, 0);
            acc = __builtin_amdgcn_mfma_f32_16x16x32_bf16(af1, bs[nt][1], acc, 0, 0, 0);
            sc[nt] = acc;
        }

        // ---- exp2 + denominator; pack E directly as K=16 A-frags ----
        short4v epk[4];
        #pragma unroll
        for (int nt = 0; nt < 4; ++nt) {
            float e0 = __builtin_amdgcn_exp2f(sc[nt][0]);
            float e1 = __builtin_amdgcn_exp2f(sc[nt][1]);
            float e2 = __builtin_amdgcn_exp2f(sc[nt][2]);
            float e3 = __builtin_amdgcn_exp2f(sc[nt][3]);
            lacc[nt] += (e0 + e1) + (e2 + e3);
            short4v ep = {(short)f2bf(e0), (short)f2bf(e1), (short)f2bf(e2), (short)f2bf(e3)};
            epk[nt] = ep;
        }

        // ---- accum GEMM (K=16): o'[q][c] += E · Kcp2 frags ----
        #pragma unroll
        for (int cb = 0; cb < 4; ++cb) {
            #pragma unroll
            for (int nt = 0; nt < 4; ++nt)
                o[nt][cb] = __builtin_amdgcn_mfma_f32_16x16x16bf16_1k(epk[nt], kb[cb], o[nt][cb], 0, 0, 0);
        }

        // rotate prefetched operands
        a0 = na0; a1 = na1;
        #pragma unroll
        for (int cb = 0; cb < 4; ++cb) kb[cb] = nkb[cb];
    }

    // ---- denominator: quad-reduce then stash per wave ----
    #pragma unroll
    for (int nt = 0; nt < 4; ++nt) {
        lacc[nt] += __shfl_xor(lacc[nt], 16);
        lacc[nt] += __shfl_xor(lacc[nt], 32);
    }
    if (quad == 0)
        #pragma unroll
        for (int nt = 0; nt < 4; ++nt) wredl[w][nt * 16 + lq] = lacc[nt];

    // ---- cross-wave combine via LDS overlay (2 rounds) ----
    float* Ol = (float*)smem;   // [4][64 c][66] fp32 = 67584 B
    __syncthreads();            // Sl reads done; wredl visible
    if (w < 4) {
        #pragma unroll
        for (int nt = 0; nt < 4; ++nt)
            #pragma unroll
            for (int cb = 0; cb < 4; ++cb)
                #pragma unroll
                for (int r = 0; r < 4; ++r)
                    Ol[(w * 64 + 16 * cb + lq) * 66 + nt * 16 + quad * 4 + r] = o[nt][cb][r];
    }
    __syncthreads();
    if (w >= 4) {
        #pragma unroll
        for (int nt = 0; nt < 4; ++nt)
            #pragma unroll
            for (int cb = 0; cb < 4; ++cb)
                #pragma unroll
                for (int r = 0; r < 4; ++r)
                    Ol[((w - 4) * 64 + 16 * cb + lq) * 66 + nt * 16 + quad * 4 + r] += o[nt][cb][r];
    }
    __syncthreads();

    // ---- final: out[c][q0+q] = sum of 4 buffers / l_q ----
    float* og = out + (size_t)b * Cn * Pn;
    #pragma unroll
    for (int k = 0; k < 8; ++k) {
        int idx = k * 512 + t;
        int c = idx >> 6, q = idx & 63;
        float lsum = ((wredl[0][q] + wredl[1][q]) + (wredl[2][q] + wredl[3][q])) +
                     ((wredl[4][q] + wredl[5][q]) + (wredl[6][q] + wredl[7][q]));
        float v = ((Ol[c * 66 + q] + Ol[(64 + c) * 66 + q]) +
                   (Ol[(128 + c) * 66 + q] + Ol[(192 + c) * 66 + q])) / lsum;
        og[(size_t)c * Pn + q0 + q] = v;
    }
}

// ---------------------------------------------------------------------------
extern "C" void kernel_launch(void* const* d_in, const int* in_sizes, int n_in,
                              void* d_out, int out_size, void* d_ws, size_t ws_size,
                              hipStream_t stream) {
    const float* fg = (const float*)d_in[0];
    float* out = (float*)d_out;
    bfu*   Kpc  = (bfu*)d_ws;                              // 2 MB  bf16 [B][P][C]
    bfu*   Kcp2 = Kpc + (size_t)Bn * Pn * Cn;              // 2 MB  bf16 [B][P/16][C][16]
    float* S    = (float*)(Kcp2 + (size_t)Bn * Pn * Cn);   // 4 MB  fp32 [B][C][P] (pre-scaled by log2e)

    prep_kernel <<<768, 256, 0, stream>>>(fg, Kpc, Kcp2, S);
    flash_kernel<<<Bn * 64, 512, 0, stream>>>(Kpc, Kcp2, S, out);
}